// Round 3
// baseline (865.597 us; speedup 1.0000x reference)
//
#include <hip/hip_runtime.h>
#include <hip/hip_bf16.h>

typedef __attribute__((ext_vector_type(8))) short bf16x8;
typedef __attribute__((ext_vector_type(4))) float f32x4;

__device__ __forceinline__ short f2bf_bits(float f) {
    __hip_bfloat16 h = __float2bfloat16(f);
    short s;
    __builtin_memcpy(&s, &h, 2);
    return s;
}

// load 8 contiguous elements -> bf16x8 (fp32 source converts RNE)
__device__ __forceinline__ bf16x8 load8(const float* p) {
    float4 a = *(const float4*)p;
    float4 b = *(const float4*)(p + 4);
    bf16x8 r;
    r[0] = f2bf_bits(a.x); r[1] = f2bf_bits(a.y);
    r[2] = f2bf_bits(a.z); r[3] = f2bf_bits(a.w);
    r[4] = f2bf_bits(b.x); r[5] = f2bf_bits(b.y);
    r[6] = f2bf_bits(b.z); r[7] = f2bf_bits(b.w);
    return r;
}
__device__ __forceinline__ bf16x8 load8(const __hip_bfloat16* p) {
    return *(const bf16x8*)p;
}

__device__ __forceinline__ void store_out(__hip_bfloat16* p, float v) {
    *p = __float2bfloat16(v);
}
__device__ __forceinline__ void store_out(float* p, float v) { *p = v; }

// ---------------------------------------------------------------------------
// GEMM: C[m,n] = sum_k A[m,k]*B[n,k] + bias[n], bf16 MFMA, fp32 accum
// 128x128 tile, BK=32, 4 waves of 64x64 (4x4 of 16x16x32 MFMA)
// ---------------------------------------------------------------------------
#define LDSS 40  // padded LDS row stride (elements), 16B aligned

template <typename TA, typename TB, typename TC>
__global__ __launch_bounds__(256) void gemm_bt_bias(
    const TA* __restrict__ A,                // M x K
    const TB* __restrict__ B,                // N x K
    const float* __restrict__ bias,          // N
    TC* __restrict__ C,                      // M x N
    int M, int N, int K)
{
    __shared__ short As[128 * LDSS];
    __shared__ short Bs[128 * LDSS];

    const int tid  = threadIdx.x;
    const int lane = tid & 63;
    const int wid  = tid >> 6;
    const int quad = lane >> 4;
    const int m16  = lane & 15;

    const int mBase = blockIdx.y * 128;
    const int nBase = blockIdx.x * 128;
    const int wm = (wid >> 1) * 64;
    const int wn = (wid & 1) * 64;

    f32x4 acc[4][4] = {};

    const int srow = tid >> 2;          // 0..63
    const int sgrp = (tid & 3) * 8;     // k-offset 0,8,16,24

    for (int kt = 0; kt < K; kt += 32) {
        __syncthreads();
        for (int p = 0; p < 2; ++p) {
            int r = srow + p * 64;
            *(bf16x8*)(&As[r * LDSS + sgrp]) =
                load8(A + (size_t)(mBase + r) * K + kt + sgrp);
            *(bf16x8*)(&Bs[r * LDSS + sgrp]) =
                load8(B + (size_t)(nBase + r) * K + kt + sgrp);
        }
        __syncthreads();

        bf16x8 afr[4], bfr[4];
        #pragma unroll
        for (int i = 0; i < 4; ++i)
            afr[i] = *(const bf16x8*)(&As[(wm + 16 * i + m16) * LDSS + quad * 8]);
        #pragma unroll
        for (int j = 0; j < 4; ++j)
            bfr[j] = *(const bf16x8*)(&Bs[(wn + 16 * j + m16) * LDSS + quad * 8]);
        #pragma unroll
        for (int i = 0; i < 4; ++i)
            #pragma unroll
            for (int j = 0; j < 4; ++j)
                acc[i][j] = __builtin_amdgcn_mfma_f32_16x16x32_bf16(
                    afr[i], bfr[j], acc[i][j], 0, 0, 0);
    }

    float bv[4];
    #pragma unroll
    for (int j = 0; j < 4; ++j)
        bv[j] = bias[nBase + wn + 16 * j + m16];

    #pragma unroll
    for (int i = 0; i < 4; ++i) {
        #pragma unroll
        for (int j = 0; j < 4; ++j) {
            int col = nBase + wn + 16 * j + m16;
            #pragma unroll
            for (int r = 0; r < 4; ++r) {
                int row = mBase + wm + 16 * i + quad * 4 + r;
                store_out(&C[(size_t)row * N + col], acc[i][j][r] + bv[j]);
            }
        }
    }
}

// ---------------------------------------------------------------------------
// RoPE in-place on q (heads 0..23) and k (cols 3072..3327) of qkv (T x 3584)
// ---------------------------------------------------------------------------
__global__ void rope_kernel(__hip_bfloat16* __restrict__ qkv,
                            const float* __restrict__ cosb,
                            const float* __restrict__ sinb, int T)
{
    int idx = blockIdx.x * 256 + threadIdx.x;
    int total = T * 26 * 64;
    if (idx >= total) return;
    int d = idx & 63;
    int h = (idx >> 6) % 26;
    int t = idx / (26 * 64);
    int col = (h < 24) ? h * 128 : 3072 + (h - 24) * 128;
    size_t base = (size_t)t * 3584 + col + d;
    float x1 = __bfloat162float(qkv[base]);
    float x2 = __bfloat162float(qkv[base + 64]);
    float c  = cosb[t * 64 + d];
    float s  = sinb[t * 64 + d];
    qkv[base]      = __float2bfloat16(x1 * c - x2 * s);
    qkv[base + 64] = __float2bfloat16(x2 * c + x1 * s);
}

// ---------------------------------------------------------------------------
// Flash attention, sliding-window causal, GQA (24 q heads -> 2 kv heads)
// Block: 256 thr = 4 waves; block handles 64 queries x 1 head; wave = 16 q.
// qkv layout per row: [0,3072) q | [3072,3328) k | [3328,3584) v
// ---------------------------------------------------------------------------
__global__ __launch_bounds__(256) void attn_kernel(
    const __hip_bfloat16* __restrict__ qkv,  // T x 3584 (rope applied)
    __hip_bfloat16* __restrict__ out,        // T x 3072
    const int* __restrict__ seq_len_p, const int* __restrict__ window_p)
{
    const int S = seq_len_p[0];
    const int window = window_p[0];

    const int g = blockIdx.x;
    const int h = blockIdx.y;
    const int kvh = h / 12;

    const int tid  = threadIdx.x;
    const int lane = tid & 63;
    const int wid  = tid >> 6;
    const int quad = lane >> 4;
    const int m16  = lane & 15;

    const int qb_global = g * 64;
    const int b  = qb_global / S;
    const int qb = qb_global - b * S;   // seq-local base

    __shared__ short Ks[32 * 136];      // [key][d], stride 136
    __shared__ short Vt[128 * 40];      // [d][key], stride 40
    __shared__ short Ps[4 * 16 * 40];   // per-wave P tile [q][key], stride 40
    short* Pw = &Ps[wid * 16 * 40];

    // Q fragments (A-operand layout): q = wid*16 + m16, k-dim chunks of 32
    bf16x8 qf[4];
    {
        const __hip_bfloat16* qp =
            qkv + (size_t)(qb_global + wid * 16 + m16) * 3584 + h * 128;
        #pragma unroll
        for (int dc = 0; dc < 4; ++dc)
            qf[dc] = *(const bf16x8*)(qp + dc * 32 + quad * 8);
    }

    f32x4 accO[8] = {};
    float mrow[4], lrow[4];
    #pragma unroll
    for (int r = 0; r < 4; ++r) { mrow[r] = -3.0e38f; lrow[r] = 0.0f; }

    const float scale = 0.088388347648318447f;  // 1/sqrt(128)

    int ka0 = qb - window + 1;
    if (ka0 < 0) ka0 = 0;
    ka0 &= ~31;
    const int kend = qb + 64;

    for (int kt = ka0; kt < kend; kt += 32) {
        __syncthreads();
        // stage K tile [32 x 128] and V^T tile [128 x 32]
        #pragma unroll
        for (int p = 0; p < 2; ++p) {
            int L   = tid + p * 256;
            int key = L >> 4;
            int d0  = (L & 15) * 8;
            size_t rowb = (size_t)(b * S + kt + key) * 3584 + kvh * 128;
            bf16x8 k8 = *(const bf16x8*)(qkv + rowb + 3072 + d0);
            *(bf16x8*)(&Ks[key * 136 + d0]) = k8;
            bf16x8 v8 = *(const bf16x8*)(qkv + rowb + 3328 + d0);
            #pragma unroll
            for (int i2 = 0; i2 < 8; ++i2)
                Vt[(d0 + i2) * 40 + key] = v8[i2];
        }
        __syncthreads();

        // S = Q K^T : two 16x16 tiles (keys kt+st*16 .. +15)
        f32x4 sacc[2] = {};
        #pragma unroll
        for (int st = 0; st < 2; ++st)
            #pragma unroll
            for (int dc = 0; dc < 4; ++dc) {
                bf16x8 kf = *(const bf16x8*)(
                    &Ks[(st * 16 + m16) * 136 + dc * 32 + quad * 8]);
                sacc[st] = __builtin_amdgcn_mfma_f32_16x16x32_bf16(
                    qf[dc], kf, sacc[st], 0, 0, 0);
            }

        // online softmax. C-layout: row q = quad*4+r, col key = m16
        const int qrow_base = qb + wid * 16 + quad * 4;
        float p0[4], p1[4], alpha[4], rsum[4];
        #pragma unroll
        for (int r = 0; r < 4; ++r) {
            int qr = qrow_base + r;
            int d0v = qr - (kt + m16);
            int d1v = qr - (kt + 16 + m16);
            bool v0 = (d0v >= 0) && (d0v < window);
            bool v1 = (d1v >= 0) && (d1v < window);
            float s0 = v0 ? sacc[0][r] * scale : -3.0e38f;
            float s1 = v1 ? sacc[1][r] * scale : -3.0e38f;
            float mx = fmaxf(s0, s1);
            #pragma unroll
            for (int off = 1; off < 16; off <<= 1)
                mx = fmaxf(mx, __shfl_xor(mx, off, 64));
            float mn = fmaxf(mrow[r], mx);
            alpha[r] = __expf(mrow[r] - mn);
            mrow[r] = mn;
            p0[r] = v0 ? __expf(s0 - mn) : 0.0f;
            p1[r] = v1 ? __expf(s1 - mn) : 0.0f;
            float sm = p0[r] + p1[r];
            #pragma unroll
            for (int off = 1; off < 16; off <<= 1)
                sm += __shfl_xor(sm, off, 64);
            rsum[r] = sm;
        }

        // P -> wave-private LDS (C-layout write, A-layout read)
        #pragma unroll
        for (int r = 0; r < 4; ++r) {
            Pw[(quad * 4 + r) * 40 + m16]      = f2bf_bits(p0[r]);
            Pw[(quad * 4 + r) * 40 + 16 + m16] = f2bf_bits(p1[r]);
        }
        #pragma unroll
        for (int r = 0; r < 4; ++r)
            lrow[r] = lrow[r] * alpha[r] + rsum[r];
        #pragma unroll
        for (int dt = 0; dt < 8; ++dt)
            #pragma unroll
            for (int r = 0; r < 4; ++r)
                accO[dt][r] *= alpha[r];

        __syncthreads();  // order Pw write -> read (uniform across block)

        bf16x8 pf = *(const bf16x8*)(&Pw[m16 * 40 + quad * 8]);
        #pragma unroll
        for (int dt = 0; dt < 8; ++dt) {
            bf16x8 vf = *(const bf16x8*)(&Vt[(dt * 16 + m16) * 40 + quad * 8]);
            accO[dt] = __builtin_amdgcn_mfma_f32_16x16x32_bf16(
                pf, vf, accO[dt], 0, 0, 0);
        }
    }

    // epilogue: O /= l, store bf16
    #pragma unroll
    for (int r = 0; r < 4; ++r) {
        int t = qb_global + wid * 16 + quad * 4 + r;
        float inv = 1.0f / lrow[r];
        __hip_bfloat16* op = out + (size_t)t * 3072 + h * 128;
        #pragma unroll
        for (int dt = 0; dt < 8; ++dt)
            op[dt * 16 + m16] = __float2bfloat16(accO[dt][r] * inv);
    }
}

// ---------------------------------------------------------------------------
extern "C" void kernel_launch(void* const* d_in, const int* in_sizes, int n_in,
                              void* d_out, int out_size, void* d_ws, size_t ws_size,
                              hipStream_t stream) {
    const float* hidden = (const float*)d_in[0];
    const float* w_qkv  = (const float*)d_in[1];
    const float* b_qkv  = (const float*)d_in[2];
    const float* w_o    = (const float*)d_in[3];
    const float* b_o    = (const float*)d_in[4];
    const float* cosb   = (const float*)d_in[5];
    const float* sinb   = (const float*)d_in[6];
    const int* seq_len_p = (const int*)d_in[7];
    const int* window_p  = (const int*)d_in[8];

    const int HID  = in_sizes[4];            // 3072
    const int NQKV = in_sizes[2];            // 3584
    const int T    = in_sizes[0] / HID;      // 4096

    __hip_bfloat16* qkv = (__hip_bfloat16*)d_ws;
    size_t qkv_bytes = ((size_t)T * NQKV * 2 + 255) & ~(size_t)255;
    __hip_bfloat16* attn_out = (__hip_bfloat16*)((char*)d_ws + qkv_bytes);

    dim3 blk(256);

    // 1) qkv = hidden @ w_qkv^T + b_qkv   (fp32 in, bf16 out)
    gemm_bt_bias<float, float, __hip_bfloat16>
        <<<dim3(NQKV / 128, T / 128), blk, 0, stream>>>(
        hidden, w_qkv, b_qkv, qkv, T, NQKV, HID);

    // 2) RoPE in place on q + k
    int total = T * 26 * 64;
    rope_kernel<<<dim3((total + 255) / 256), blk, 0, stream>>>(qkv, cosb, sinb, T);

    // 3) attention -> attn_out (T x 3072, bf16)
    attn_kernel<<<dim3(T / 64, 24), blk, 0, stream>>>(qkv, attn_out, seq_len_p, window_p);

    // 4) out = attn_out @ w_o^T + b_o   (bf16 x fp32 in, fp32 OUT)
    gemm_bt_bias<__hip_bfloat16, float, float>
        <<<dim3(HID / 128, T / 128), blk, 0, stream>>>(
        attn_out, w_o, b_o, (float*)d_out, T, HID, HID);
}

// Round 4
// 602.063 us; speedup vs baseline: 1.4377x; 1.4377x over previous
//
#include <hip/hip_runtime.h>
#include <hip/hip_bf16.h>

typedef __attribute__((ext_vector_type(8))) short bf16x8;
typedef __attribute__((ext_vector_type(4))) float f32x4;

__device__ __forceinline__ short f2bf_bits(float f) {
    __hip_bfloat16 h = __float2bfloat16(f);
    short s;
    __builtin_memcpy(&s, &h, 2);
    return s;
}

__device__ __forceinline__ bf16x8 load8(const float* p) {
    float4 a = *(const float4*)p;
    float4 b = *(const float4*)(p + 4);
    bf16x8 r;
    r[0] = f2bf_bits(a.x); r[1] = f2bf_bits(a.y);
    r[2] = f2bf_bits(a.z); r[3] = f2bf_bits(a.w);
    r[4] = f2bf_bits(b.x); r[5] = f2bf_bits(b.y);
    r[6] = f2bf_bits(b.z); r[7] = f2bf_bits(b.w);
    return r;
}
__device__ __forceinline__ bf16x8 load8(const __hip_bfloat16* p) {
    return *(const bf16x8*)p;
}

__device__ __forceinline__ void store_out(__hip_bfloat16* p, float v) {
    *p = __float2bfloat16(v);
}
__device__ __forceinline__ void store_out(float* p, float v) { *p = v; }

// async global->LDS 16B per lane; lds base must be wave-uniform
__device__ __forceinline__ void stage16(const __hip_bfloat16* g, short* lds_base, int lane) {
#if defined(__has_builtin) && __has_builtin(__builtin_amdgcn_global_load_lds)
    __builtin_amdgcn_global_load_lds(
        (__attribute__((address_space(1))) void*)g,
        (__attribute__((address_space(3))) void*)lds_base, 16, 0, 0);
#else
    *(bf16x8*)(lds_base + lane * 8) = *(const bf16x8*)g;
#endif
}

// ---------------------------------------------------------------------------
// f32 -> bf16 bulk convert (8 elems/thread)
// ---------------------------------------------------------------------------
__global__ void cvt_f32_bf16(const float* __restrict__ in,
                             __hip_bfloat16* __restrict__ out, int n8) {
    int i = blockIdx.x * 256 + threadIdx.x;
    if (i < n8)
        *(bf16x8*)((short*)out + (size_t)i * 8) = load8(in + (size_t)i * 8);
}

// ---------------------------------------------------------------------------
// GEMM (bf16 x bf16): C = A(MxK) * B(NxK)^T + bias. global_load_lds staging,
// unpadded [128][32] LDS tiles (m97 structure), 4 waves of 64x64.
// ---------------------------------------------------------------------------
template <typename TC>
__global__ __launch_bounds__(256) void gemm_bt_lds(
    const __hip_bfloat16* __restrict__ A, const __hip_bfloat16* __restrict__ B,
    const float* __restrict__ bias, TC* __restrict__ C, int M, int N, int K)
{
    __shared__ short As[128 * 32];
    __shared__ short Bs[128 * 32];

    const int tid  = threadIdx.x;
    const int lane = tid & 63;
    const int wid  = tid >> 6;
    const int quad = lane >> 4;
    const int m16  = lane & 15;

    const int mBase = blockIdx.y * 128;
    const int nBase = blockIdx.x * 128;
    const int wm = (wid >> 1) * 64;
    const int wn = (wid & 1) * 64;

    f32x4 acc[4][4] = {};

    const int lrow = lane >> 2;        // 0..15
    const int lcol = (lane & 3) * 8;   // 0,8,16,24
    const __hip_bfloat16* Abase = A + (size_t)(mBase + wid * 32 + lrow) * K + lcol;
    const __hip_bfloat16* Bbase = B + (size_t)(nBase + wid * 32 + lrow) * K + lcol;
    short* AsW = &As[wid * 32 * 32];
    short* BsW = &Bs[wid * 32 * 32];

    for (int kt = 0; kt < K; kt += 32) {
        __syncthreads();
        stage16(Abase + kt,          AsW,           lane);
        stage16(Abase + 16 * K + kt, AsW + 16 * 32, lane);
        stage16(Bbase + kt,          BsW,           lane);
        stage16(Bbase + 16 * K + kt, BsW + 16 * 32, lane);
        __syncthreads();

        bf16x8 afr[4], bfr[4];
        #pragma unroll
        for (int i = 0; i < 4; ++i)
            afr[i] = *(const bf16x8*)(&As[(wm + 16 * i + m16) * 32 + quad * 8]);
        #pragma unroll
        for (int j = 0; j < 4; ++j)
            bfr[j] = *(const bf16x8*)(&Bs[(wn + 16 * j + m16) * 32 + quad * 8]);
        #pragma unroll
        for (int i = 0; i < 4; ++i)
            #pragma unroll
            for (int j = 0; j < 4; ++j)
                acc[i][j] = __builtin_amdgcn_mfma_f32_16x16x32_bf16(
                    afr[i], bfr[j], acc[i][j], 0, 0, 0);
    }

    float bv[4];
    #pragma unroll
    for (int j = 0; j < 4; ++j)
        bv[j] = bias[nBase + wn + 16 * j + m16];

    #pragma unroll
    for (int i = 0; i < 4; ++i)
        #pragma unroll
        for (int j = 0; j < 4; ++j) {
            int col = nBase + wn + 16 * j + m16;
            #pragma unroll
            for (int r = 0; r < 4; ++r) {
                int row = mBase + wm + 16 * i + quad * 4 + r;
                store_out(&C[(size_t)row * N + col], acc[i][j][r] + bv[j]);
            }
        }
}

// ---------------------------------------------------------------------------
// Fallback GEMM (fp32 inputs converted inline) — proven R3 path
// ---------------------------------------------------------------------------
#define LDSS 40

template <typename TA, typename TB, typename TC>
__global__ __launch_bounds__(256) void gemm_bt_bias(
    const TA* __restrict__ A, const TB* __restrict__ B,
    const float* __restrict__ bias, TC* __restrict__ C, int M, int N, int K)
{
    __shared__ short As[128 * LDSS];
    __shared__ short Bs[128 * LDSS];

    const int tid  = threadIdx.x;
    const int lane = tid & 63;
    const int wid  = tid >> 6;
    const int quad = lane >> 4;
    const int m16  = lane & 15;

    const int mBase = blockIdx.y * 128;
    const int nBase = blockIdx.x * 128;
    const int wm = (wid >> 1) * 64;
    const int wn = (wid & 1) * 64;

    f32x4 acc[4][4] = {};
    const int srow = tid >> 2;
    const int sgrp = (tid & 3) * 8;

    for (int kt = 0; kt < K; kt += 32) {
        __syncthreads();
        for (int p = 0; p < 2; ++p) {
            int r = srow + p * 64;
            *(bf16x8*)(&As[r * LDSS + sgrp]) =
                load8(A + (size_t)(mBase + r) * K + kt + sgrp);
            *(bf16x8*)(&Bs[r * LDSS + sgrp]) =
                load8(B + (size_t)(nBase + r) * K + kt + sgrp);
        }
        __syncthreads();

        bf16x8 afr[4], bfr[4];
        #pragma unroll
        for (int i = 0; i < 4; ++i)
            afr[i] = *(const bf16x8*)(&As[(wm + 16 * i + m16) * LDSS + quad * 8]);
        #pragma unroll
        for (int j = 0; j < 4; ++j)
            bfr[j] = *(const bf16x8*)(&Bs[(wn + 16 * j + m16) * LDSS + quad * 8]);
        #pragma unroll
        for (int i = 0; i < 4; ++i)
            #pragma unroll
            for (int j = 0; j < 4; ++j)
                acc[i][j] = __builtin_amdgcn_mfma_f32_16x16x32_bf16(
                    afr[i], bfr[j], acc[i][j], 0, 0, 0);
    }

    float bv[4];
    #pragma unroll
    for (int j = 0; j < 4; ++j)
        bv[j] = bias[nBase + wn + 16 * j + m16];

    #pragma unroll
    for (int i = 0; i < 4; ++i)
        #pragma unroll
        for (int j = 0; j < 4; ++j) {
            int col = nBase + wn + 16 * j + m16;
            #pragma unroll
            for (int r = 0; r < 4; ++r) {
                int row = mBase + wm + 16 * i + quad * 4 + r;
                store_out(&C[(size_t)row * N + col], acc[i][j][r] + bv[j]);
            }
        }
}

// ---------------------------------------------------------------------------
// RoPE in-place on q (heads 0..23) and k (cols 3072..3327) of qkv (T x 3584)
// ---------------------------------------------------------------------------
__global__ void rope_kernel(__hip_bfloat16* __restrict__ qkv,
                            const float* __restrict__ cosb,
                            const float* __restrict__ sinb, int T)
{
    int idx = blockIdx.x * 256 + threadIdx.x;
    int total = T * 26 * 64;
    if (idx >= total) return;
    int d = idx & 63;
    int h = (idx >> 6) % 26;
    int t = idx / (26 * 64);
    int col = (h < 24) ? h * 128 : 3072 + (h - 24) * 128;
    size_t base = (size_t)t * 3584 + col + d;
    float x1 = __bfloat162float(qkv[base]);
    float x2 = __bfloat162float(qkv[base + 64]);
    float c  = cosb[t * 64 + d];
    float s  = sinb[t * 64 + d];
    qkv[base]      = __float2bfloat16(x1 * c - x2 * s);
    qkv[base + 64] = __float2bfloat16(x2 * c + x1 * s);
}

// ---------------------------------------------------------------------------
// Flash attention v2: S^T = K*Q^T (in-lane softmax reduction), 128 q/block,
// conflict-free V^T staging, K frags from global (L2-hot).
// ---------------------------------------------------------------------------
__global__ __launch_bounds__(256, 3) void attn_kernel(
    const __hip_bfloat16* __restrict__ qkv,  // T x 3584 (rope applied)
    __hip_bfloat16* __restrict__ out,        // T x 3072
    const int* __restrict__ seq_len_p, const int* __restrict__ window_p)
{
    const int S = seq_len_p[0];
    const int window = window_p[0];
    const float scale = 0.088388347648318447f;  // 1/sqrt(128)

    const int h   = blockIdx.y;
    const int kvh = h / 12;
    const int tid  = threadIdx.x;
    const int lane = tid & 63;
    const int wid  = tid >> 6;
    const int quad = lane >> 4;
    const int m16  = lane & 15;

    const int qb_global = blockIdx.x * 128;
    const int b  = qb_global / S;
    const int qb = qb_global - b * S;

    __shared__ short Vt[128 * 72];      // V^T: V[key][d] at [d*72 + key + ((d>>3)&1)*32]
    __shared__ short Ps[4][32 * 40];    // per-wave P [q][key], stride 40

    const size_t kvrow0 = (size_t)(b * S) * 3584 + 3072 + kvh * 128;

    // Q fragments: wave covers q rows qb_global + wid*32 + qt*16 + m16
    bf16x8 qf[2][4];
    {
        const __hip_bfloat16* qp =
            qkv + (size_t)(qb_global + wid * 32 + m16) * 3584 + h * 128;
        #pragma unroll
        for (int qt = 0; qt < 2; ++qt)
            #pragma unroll
            for (int dc = 0; dc < 4; ++dc)
                qf[qt][dc] = *(const bf16x8*)(qp + qt * 16 * 3584 + dc * 32 + quad * 8);
    }

    f32x4 accO[2][8] = {};
    float mqt[2] = {-1.0e30f, -1.0e30f};
    float lqt[2] = {0.f, 0.f};

    int ka0 = qb - window + 1;
    if (ka0 < 0) ka0 = 0;
    ka0 &= ~31;
    const int kend = qb + 128;

    for (int kt = ka0; kt < kend; kt += 32) {
        __syncthreads();
        // stage V^T, conflict-free: lane group -> key = L&31, d-chunk = L>>5
        #pragma unroll
        for (int p = 0; p < 2; ++p) {
            int L   = tid + p * 256;
            int key = L & 31;
            int gg  = L >> 5;          // 0..15
            int d0  = gg * 8;
            bf16x8 v8 = *(const bf16x8*)(qkv + kvrow0 + (size_t)(kt + key) * 3584 + 256 + d0);
            short* dst = &Vt[d0 * 72 + key + (gg & 1) * 32];
            #pragma unroll
            for (int i2 = 0; i2 < 8; ++i2) dst[i2 * 72] = v8[i2];
        }
        __syncthreads();

        // S^T = K * Q^T (K frags direct from global)
        f32x4 sacc[2][2] = {};   // [st][qt]
        #pragma unroll
        for (int st = 0; st < 2; ++st) {
            const __hip_bfloat16* kp =
                qkv + kvrow0 + (size_t)(kt + st * 16 + m16) * 3584;
            #pragma unroll
            for (int dc = 0; dc < 4; ++dc) {
                bf16x8 kf = *(const bf16x8*)(kp + dc * 32 + quad * 8);
                sacc[st][0] = __builtin_amdgcn_mfma_f32_16x16x32_bf16(
                    kf, qf[0][dc], sacc[st][0], 0, 0, 0);
                sacc[st][1] = __builtin_amdgcn_mfma_f32_16x16x32_bf16(
                    kf, qf[1][dc], sacc[st][1], 0, 0, 0);
            }
        }

        // online softmax per qt; S^T C-layout: col m16 = q, row quad*4+r = key
        #pragma unroll
        for (int qt = 0; qt < 2; ++qt) {
            const int dl_base = (qb + wid * 32 + qt * 16 + m16) - (kt + quad * 4);
            float sv[2][4];
            float smax = -3.0e38f;
            #pragma unroll
            for (int st = 0; st < 2; ++st)
                #pragma unroll
                for (int r = 0; r < 4; ++r) {
                    int dl = dl_base - st * 16 - r;
                    bool valid = ((unsigned)dl < (unsigned)window);
                    sv[st][r] = valid ? sacc[st][qt][r] * scale : -3.0e38f;
                    smax = fmaxf(smax, sv[st][r]);
                }
            smax = fmaxf(smax, __shfl_xor(smax, 16, 64));
            smax = fmaxf(smax, __shfl_xor(smax, 32, 64));
            float mn = fmaxf(mqt[qt], smax);
            float alpha = __expf(mqt[qt] - mn);
            mqt[qt] = mn;

            float psum = 0.f;
            short* prow = &Ps[wid][(qt * 16 + m16) * 40];
            #pragma unroll
            for (int st = 0; st < 2; ++st)
                #pragma unroll
                for (int r = 0; r < 4; ++r) {
                    float pp = __expf(sv[st][r] - mn);
                    psum += pp;
                    prow[st * 16 + quad * 4 + r] = f2bf_bits(pp);
                }
            psum += __shfl_xor(psum, 16, 64);
            psum += __shfl_xor(psum, 32, 64);
            lqt[qt] = lqt[qt] * alpha + psum;

            float a0 = __shfl(alpha, quad * 4 + 0, 64);
            float a1 = __shfl(alpha, quad * 4 + 1, 64);
            float a2 = __shfl(alpha, quad * 4 + 2, 64);
            float a3 = __shfl(alpha, quad * 4 + 3, 64);
            #pragma unroll
            for (int dt = 0; dt < 8; ++dt) {
                accO[qt][dt][0] *= a0;
                accO[qt][dt][1] *= a1;
                accO[qt][dt][2] *= a2;
                accO[qt][dt][3] *= a3;
            }
        }

        // PV: A = P (wave-private LDS), B = V^T frag
        bf16x8 pf0 = *(const bf16x8*)(&Ps[wid][(0  + m16) * 40 + quad * 8]);
        bf16x8 pf1 = *(const bf16x8*)(&Ps[wid][(16 + m16) * 40 + quad * 8]);
        #pragma unroll
        for (int dt = 0; dt < 8; ++dt) {
            int row = dt * 16 + m16;
            bf16x8 vf = *(const bf16x8*)(&Vt[row * 72 + quad * 8 + ((row >> 3) & 1) * 32]);
            accO[0][dt] = __builtin_amdgcn_mfma_f32_16x16x32_bf16(pf0, vf, accO[0][dt], 0, 0, 0);
            accO[1][dt] = __builtin_amdgcn_mfma_f32_16x16x32_bf16(pf1, vf, accO[1][dt], 0, 0, 0);
        }
    }

    // epilogue: O /= l
    #pragma unroll
    for (int qt = 0; qt < 2; ++qt) {
        float li[4];
        #pragma unroll
        for (int r = 0; r < 4; ++r)
            li[r] = 1.0f / __shfl(lqt[qt], quad * 4 + r, 64);
        #pragma unroll
        for (int r = 0; r < 4; ++r) {
            int t = qb_global + wid * 32 + qt * 16 + quad * 4 + r;
            __hip_bfloat16* op = out + (size_t)t * 3072 + h * 128 + m16;
            #pragma unroll
            for (int dt = 0; dt < 8; ++dt)
                op[dt * 16] = __float2bfloat16(accO[qt][dt][r] * li[r]);
        }
    }
}

// ---------------------------------------------------------------------------
extern "C" void kernel_launch(void* const* d_in, const int* in_sizes, int n_in,
                              void* d_out, int out_size, void* d_ws, size_t ws_size,
                              hipStream_t stream) {
    const float* hidden = (const float*)d_in[0];
    const float* w_qkv  = (const float*)d_in[1];
    const float* b_qkv  = (const float*)d_in[2];
    const float* w_o    = (const float*)d_in[3];
    const float* b_o    = (const float*)d_in[4];
    const float* cosb   = (const float*)d_in[5];
    const float* sinb   = (const float*)d_in[6];
    const int* seq_len_p = (const int*)d_in[7];
    const int* window_p  = (const int*)d_in[8];

    const int HID  = in_sizes[4];            // 3072
    const int NQKV = in_sizes[2];            // 3584
    const int T    = in_sizes[0] / HID;      // 4096

    size_t off = 0;
    auto alloc = [&](size_t bytes) {
        char* p = (char*)d_ws + off;
        off = (off + bytes + 255) & ~(size_t)255;
        return p;
    };
    __hip_bfloat16* qkv      = (__hip_bfloat16*)alloc((size_t)T * NQKV * 2);
    __hip_bfloat16* attn_out = (__hip_bfloat16*)alloc((size_t)T * HID * 2);
    size_t base_need = off;
    __hip_bfloat16* hid_bf = (__hip_bfloat16*)alloc((size_t)T * HID * 2);
    __hip_bfloat16* wq_bf  = (__hip_bfloat16*)alloc((size_t)NQKV * HID * 2);
    __hip_bfloat16* wo_bf  = (__hip_bfloat16*)alloc((size_t)HID * HID * 2);
    const bool pre = (ws_size >= off);
    (void)base_need;

    dim3 blk(256);

    if (pre) {
        int n8h = T * HID / 8, n8q = NQKV * HID / 8, n8o = HID * HID / 8;
        cvt_f32_bf16<<<dim3((n8h + 255) / 256), blk, 0, stream>>>(hidden, hid_bf, n8h);
        cvt_f32_bf16<<<dim3((n8q + 255) / 256), blk, 0, stream>>>(w_qkv, wq_bf, n8q);
        cvt_f32_bf16<<<dim3((n8o + 255) / 256), blk, 0, stream>>>(w_o, wo_bf, n8o);
        gemm_bt_lds<__hip_bfloat16><<<dim3(NQKV / 128, T / 128), blk, 0, stream>>>(
            hid_bf, wq_bf, b_qkv, qkv, T, NQKV, HID);
    } else {
        gemm_bt_bias<float, float, __hip_bfloat16>
            <<<dim3(NQKV / 128, T / 128), blk, 0, stream>>>(
            hidden, w_qkv, b_qkv, qkv, T, NQKV, HID);
    }

    int total = T * 26 * 64;
    rope_kernel<<<dim3((total + 255) / 256), blk, 0, stream>>>(qkv, cosb, sinb, T);

    attn_kernel<<<dim3(T / 128, 24), blk, 0, stream>>>(qkv, attn_out, seq_len_p, window_p);

    if (pre) {
        gemm_bt_lds<float><<<dim3(HID / 128, T / 128), blk, 0, stream>>>(
            attn_out, wo_bf, b_o, (float*)d_out, T, HID, HID);
    } else {
        gemm_bt_bias<__hip_bfloat16, float, float>
            <<<dim3(HID / 128, T / 128), blk, 0, stream>>>(
            attn_out, w_o, b_o, (float*)d_out, T, HID, HID);
    }
}

// Round 6
// 578.890 us; speedup vs baseline: 1.4953x; 1.0400x over previous
//
#include <hip/hip_runtime.h>
#include <hip/hip_bf16.h>

typedef __attribute__((ext_vector_type(8))) short bf16x8;
typedef __attribute__((ext_vector_type(4))) float f32x4;

__device__ __forceinline__ short f2bf_bits(float f) {
    __hip_bfloat16 h = __float2bfloat16(f);
    short s;
    __builtin_memcpy(&s, &h, 2);
    return s;
}

__device__ __forceinline__ float bf_bits2f(short s) {
    unsigned int u = ((unsigned int)(unsigned short)s) << 16;
    float f;
    __builtin_memcpy(&f, &u, 4);
    return f;
}

__device__ __forceinline__ bf16x8 load8(const float* p) {
    float4 a = *(const float4*)p;
    float4 b = *(const float4*)(p + 4);
    bf16x8 r;
    r[0] = f2bf_bits(a.x); r[1] = f2bf_bits(a.y);
    r[2] = f2bf_bits(a.z); r[3] = f2bf_bits(a.w);
    r[4] = f2bf_bits(b.x); r[5] = f2bf_bits(b.y);
    r[6] = f2bf_bits(b.z); r[7] = f2bf_bits(b.w);
    return r;
}
__device__ __forceinline__ bf16x8 load8(const __hip_bfloat16* p) {
    return *(const bf16x8*)p;
}

__device__ __forceinline__ void store_out(__hip_bfloat16* p, float v) {
    *p = __float2bfloat16(v);
}
__device__ __forceinline__ void store_out(float* p, float v) { *p = v; }

// async global->LDS 16B per lane; lds base must be wave-uniform
__device__ __forceinline__ void stage16(const __hip_bfloat16* g, short* lds_base, int lane) {
#if defined(__has_builtin) && __has_builtin(__builtin_amdgcn_global_load_lds)
    __builtin_amdgcn_global_load_lds(
        (__attribute__((address_space(1))) void*)g,
        (__attribute__((address_space(3))) void*)lds_base, 16, 0, 0);
#else
    *(bf16x8*)(lds_base + lane * 8) = *(const bf16x8*)g;
#endif
}

// ---------------------------------------------------------------------------
// merged f32 -> bf16 bulk convert of three buffers (8 elems/thread)
// ---------------------------------------------------------------------------
__global__ void cvt3_f32_bf16(const float* __restrict__ a, short* __restrict__ da, int na8,
                              const float* __restrict__ b, short* __restrict__ db, int nb8,
                              const float* __restrict__ c, short* __restrict__ dc, int nc8) {
    int i = blockIdx.x * 256 + threadIdx.x;
    if (i < na8) {
        *(bf16x8*)(da + (size_t)i * 8) = load8(a + (size_t)i * 8);
    } else if ((i -= na8) < nb8) {
        *(bf16x8*)(db + (size_t)i * 8) = load8(b + (size_t)i * 8);
    } else if ((i -= nb8) < nc8) {
        *(bf16x8*)(dc + (size_t)i * 8) = load8(c + (size_t)i * 8);
    }
}

// ---------------------------------------------------------------------------
// GEMM (bf16 x bf16): C = A(MxK) * B(NxK)^T + bias. global_load_lds staging,
// unpadded [128][32] LDS tiles, 4 waves of 64x64, GROUP_M=8 L2 swizzle.
// ---------------------------------------------------------------------------
template <typename TC>
__global__ __launch_bounds__(256) void gemm_bt_lds(
    const __hip_bfloat16* __restrict__ A, const __hip_bfloat16* __restrict__ B,
    const float* __restrict__ bias, TC* __restrict__ C, int M, int N, int K)
{
    __shared__ short As[128 * 32];
    __shared__ short Bs[128 * 32];

    const int tid  = threadIdx.x;
    const int lane = tid & 63;
    const int wid  = tid >> 6;
    const int quad = lane >> 4;
    const int m16  = lane & 15;

    // GROUP_M=8 swizzle: 8 consecutive blocks share one B strip, 8 A strips
    const int nT = gridDim.x;
    int lin = blockIdx.y * nT + blockIdx.x;
    int grp = lin >> 3;           // / 8
    int bm8 = lin & 7;
    int bn  = grp % nT;
    int bm  = (grp / nT) * 8 + bm8;

    const int mBase = bm * 128;
    const int nBase = bn * 128;
    const int wm = (wid >> 1) * 64;
    const int wn = (wid & 1) * 64;

    f32x4 acc[4][4] = {};

    const int lrow = lane >> 2;        // 0..15
    const int lcol = (lane & 3) * 8;   // 0,8,16,24
    const __hip_bfloat16* Abase = A + (size_t)(mBase + wid * 32 + lrow) * K + lcol;
    const __hip_bfloat16* Bbase = B + (size_t)(nBase + wid * 32 + lrow) * K + lcol;
    short* AsW = &As[wid * 32 * 32];
    short* BsW = &Bs[wid * 32 * 32];

    for (int kt = 0; kt < K; kt += 32) {
        __syncthreads();
        stage16(Abase + kt,          AsW,           lane);
        stage16(Abase + 16 * K + kt, AsW + 16 * 32, lane);
        stage16(Bbase + kt,          BsW,           lane);
        stage16(Bbase + 16 * K + kt, BsW + 16 * 32, lane);
        __syncthreads();

        bf16x8 afr[4], bfr[4];
        #pragma unroll
        for (int i = 0; i < 4; ++i)
            afr[i] = *(const bf16x8*)(&As[(wm + 16 * i + m16) * 32 + quad * 8]);
        #pragma unroll
        for (int j = 0; j < 4; ++j)
            bfr[j] = *(const bf16x8*)(&Bs[(wn + 16 * j + m16) * 32 + quad * 8]);
        #pragma unroll
        for (int i = 0; i < 4; ++i)
            #pragma unroll
            for (int j = 0; j < 4; ++j)
                acc[i][j] = __builtin_amdgcn_mfma_f32_16x16x32_bf16(
                    afr[i], bfr[j], acc[i][j], 0, 0, 0);
    }

    float bv[4];
    #pragma unroll
    for (int j = 0; j < 4; ++j)
        bv[j] = bias[nBase + wn + 16 * j + m16];

    #pragma unroll
    for (int i = 0; i < 4; ++i)
        #pragma unroll
        for (int j = 0; j < 4; ++j) {
            int col = nBase + wn + 16 * j + m16;
            #pragma unroll
            for (int r = 0; r < 4; ++r) {
                int row = mBase + wm + 16 * i + quad * 4 + r;
                store_out(&C[(size_t)row * N + col], acc[i][j][r] + bv[j]);
            }
        }
}

// ---------------------------------------------------------------------------
// Fallback GEMM (fp32 inputs converted inline) — safety net if ws too small
// ---------------------------------------------------------------------------
#define LDSS 40

template <typename TA, typename TB, typename TC>
__global__ __launch_bounds__(256) void gemm_bt_bias(
    const TA* __restrict__ A, const TB* __restrict__ B,
    const float* __restrict__ bias, TC* __restrict__ C, int M, int N, int K)
{
    __shared__ short As[128 * LDSS];
    __shared__ short Bs[128 * LDSS];

    const int tid  = threadIdx.x;
    const int lane = tid & 63;
    const int wid  = tid >> 6;
    const int quad = lane >> 4;
    const int m16  = lane & 15;

    const int mBase = blockIdx.y * 128;
    const int nBase = blockIdx.x * 128;
    const int wm = (wid >> 1) * 64;
    const int wn = (wid & 1) * 64;

    f32x4 acc[4][4] = {};
    const int srow = tid >> 2;
    const int sgrp = (tid & 3) * 8;

    for (int kt = 0; kt < K; kt += 32) {
        __syncthreads();
        for (int p = 0; p < 2; ++p) {
            int r = srow + p * 64;
            *(bf16x8*)(&As[r * LDSS + sgrp]) =
                load8(A + (size_t)(mBase + r) * K + kt + sgrp);
            *(bf16x8*)(&Bs[r * LDSS + sgrp]) =
                load8(B + (size_t)(nBase + r) * K + kt + sgrp);
        }
        __syncthreads();

        bf16x8 afr[4], bfr[4];
        #pragma unroll
        for (int i = 0; i < 4; ++i)
            afr[i] = *(const bf16x8*)(&As[(wm + 16 * i + m16) * LDSS + quad * 8]);
        #pragma unroll
        for (int j = 0; j < 4; ++j)
            bfr[j] = *(const bf16x8*)(&Bs[(wn + 16 * j + m16) * LDSS + quad * 8]);
        #pragma unroll
        for (int i = 0; i < 4; ++i)
            #pragma unroll
            for (int j = 0; j < 4; ++j)
                acc[i][j] = __builtin_amdgcn_mfma_f32_16x16x32_bf16(
                    afr[i], bfr[j], acc[i][j], 0, 0, 0);
    }

    float bv[4];
    #pragma unroll
    for (int j = 0; j < 4; ++j)
        bv[j] = bias[nBase + wn + 16 * j + m16];

    #pragma unroll
    for (int i = 0; i < 4; ++i)
        #pragma unroll
        for (int j = 0; j < 4; ++j) {
            int col = nBase + wn + 16 * j + m16;
            #pragma unroll
            for (int r = 0; r < 4; ++r) {
                int row = mBase + wm + 16 * i + quad * 4 + r;
                store_out(&C[(size_t)row * N + col], acc[i][j][r] + bv[j]);
            }
        }
}

// ---------------------------------------------------------------------------
// RoPE in-place on q (heads 0..23) and k (cols 3072..3327), 8 elems/thread
// ---------------------------------------------------------------------------
__global__ void rope_kernel(__hip_bfloat16* __restrict__ qkv,
                            const float* __restrict__ cosb,
                            const float* __restrict__ sinb, int T)
{
    int idx = blockIdx.x * 256 + threadIdx.x;          // (t, h, j): j = d/8
    int total = T * 26 * 8;
    if (idx >= total) return;
    int j = idx & 7;
    int h = (idx >> 3) % 26;
    int t = idx / (26 * 8);
    int col = (h < 24) ? h * 128 : 3072 + (h - 24) * 128;
    int d0 = j * 8;
    size_t base = (size_t)t * 3584 + col + d0;
    bf16x8 x1 = *(const bf16x8*)((const short*)qkv + base);
    bf16x8 x2 = *(const bf16x8*)((const short*)qkv + base + 64);
    float4 c0 = *(const float4*)(cosb + t * 64 + d0);
    float4 c1 = *(const float4*)(cosb + t * 64 + d0 + 4);
    float4 s0 = *(const float4*)(sinb + t * 64 + d0);
    float4 s1 = *(const float4*)(sinb + t * 64 + d0 + 4);
    float cc[8] = {c0.x, c0.y, c0.z, c0.w, c1.x, c1.y, c1.z, c1.w};
    float ss[8] = {s0.x, s0.y, s0.z, s0.w, s1.x, s1.y, s1.z, s1.w};
    bf16x8 o1, o2;
    #pragma unroll
    for (int i = 0; i < 8; ++i) {
        float f1 = bf_bits2f(x1[i]);
        float f2 = bf_bits2f(x2[i]);
        o1[i] = f2bf_bits(f1 * cc[i] - f2 * ss[i]);
        o2[i] = f2bf_bits(f2 * cc[i] + f1 * ss[i]);
    }
    *(bf16x8*)((short*)qkv + base)      = o1;
    *(bf16x8*)((short*)qkv + base + 64) = o2;
}

// ---------------------------------------------------------------------------
// Flash attention v3: S^T = K*Q^T, fixed-shift softmax (no online rescale),
// interior-chunk fast path, conflict-free V^T staging.
// ---------------------------------------------------------------------------
#define SM_SHIFT 12.0f

__global__ __launch_bounds__(256, 3) void attn_kernel(
    const __hip_bfloat16* __restrict__ qkv,  // T x 3584 (rope applied)
    __hip_bfloat16* __restrict__ out,        // T x 3072
    const int* __restrict__ seq_len_p, const int* __restrict__ window_p)
{
    const int S = seq_len_p[0];
    const int window = window_p[0];
    const float scale = 0.088388347648318447f;  // 1/sqrt(128)

    const int h   = blockIdx.y;
    const int kvh = h / 12;
    const int tid  = threadIdx.x;
    const int lane = tid & 63;
    const int wid  = tid >> 6;
    const int quad = lane >> 4;
    const int m16  = lane & 15;

    const int qb_global = blockIdx.x * 128;
    const int b  = qb_global / S;
    const int qb = qb_global - b * S;

    __shared__ short Vt[128 * 72];      // V^T: V[key][d] at [d*72 + key + ((d>>3)&1)*32]
    __shared__ short Ps[4][32 * 40];    // per-wave P [q][key], stride 40

    const size_t kvrow0 = (size_t)(b * S) * 3584 + 3072 + kvh * 128;

    bf16x8 qf[2][4];
    {
        const __hip_bfloat16* qp =
            qkv + (size_t)(qb_global + wid * 32 + m16) * 3584 + h * 128;
        #pragma unroll
        for (int qt = 0; qt < 2; ++qt)
            #pragma unroll
            for (int dc = 0; dc < 4; ++dc)
                qf[qt][dc] = *(const bf16x8*)(qp + qt * 16 * 3584 + dc * 32 + quad * 8);
    }

    f32x4 accO[2][8] = {};
    float lqt[2] = {0.f, 0.f};

    int ka0 = qb - window + 1;
    if (ka0 < 0) ka0 = 0;
    ka0 &= ~31;
    const int kend = qb + 128;

    for (int kt = ka0; kt < kend; kt += 32) {
        __syncthreads();
        // stage V^T, conflict-free: key = L&31, d-chunk = L>>5
        #pragma unroll
        for (int p = 0; p < 2; ++p) {
            int L   = tid + p * 256;
            int key = L & 31;
            int gg  = L >> 5;          // 0..15
            int d0  = gg * 8;
            bf16x8 v8 = *(const bf16x8*)(qkv + kvrow0 + (size_t)(kt + key) * 3584 + 256 + d0);
            short* dst = &Vt[d0 * 72 + key + (gg & 1) * 32];
            #pragma unroll
            for (int i2 = 0; i2 < 8; ++i2) dst[i2 * 72] = v8[i2];
        }
        __syncthreads();

        // S^T = K * Q^T (K frags direct from global, L2-hot)
        f32x4 sacc[2][2] = {};   // [st][qt]
        #pragma unroll
        for (int st = 0; st < 2; ++st) {
            const __hip_bfloat16* kp =
                qkv + kvrow0 + (size_t)(kt + st * 16 + m16) * 3584;
            #pragma unroll
            for (int dc = 0; dc < 4; ++dc) {
                bf16x8 kf = *(const bf16x8*)(kp + dc * 32 + quad * 8);
                sacc[st][0] = __builtin_amdgcn_mfma_f32_16x16x32_bf16(
                    kf, qf[0][dc], sacc[st][0], 0, 0, 0);
                sacc[st][1] = __builtin_amdgcn_mfma_f32_16x16x32_bf16(
                    kf, qf[1][dc], sacc[st][1], 0, 0, 0);
            }
        }

        // fixed-shift softmax: p = exp(s*scale - SHIFT); no rescaling ever.
        // S^T C-layout: col m16 = q, row quad*4 + r + st*16 = key
        #pragma unroll
        for (int qt = 0; qt < 2; ++qt) {
            const int qmin = qb + wid * 32 + qt * 16;     // wave-uniform
            short* prow = &Ps[wid][(qt * 16 + m16) * 40];
            float psum = 0.f;
            if (kt <= qmin - 31 && kt >= qmin + 16 - window) {
                // interior: all 32 keys valid for all 16 q
                #pragma unroll
                for (int st = 0; st < 2; ++st)
                    #pragma unroll
                    for (int r = 0; r < 4; ++r) {
                        float pp = __expf(fminf(
                            sacc[st][qt][r] * scale - SM_SHIFT, 80.f));
                        psum += pp;
                        prow[st * 16 + quad * 4 + r] = f2bf_bits(pp);
                    }
            } else {
                const int dl_base = (qmin + m16) - (kt + quad * 4);
                #pragma unroll
                for (int st = 0; st < 2; ++st)
                    #pragma unroll
                    for (int r = 0; r < 4; ++r) {
                        int dl = dl_base - st * 16 - r;
                        float pp = ((unsigned)dl < (unsigned)window)
                            ? __expf(fminf(sacc[st][qt][r] * scale - SM_SHIFT, 80.f))
                            : 0.f;
                        psum += pp;
                        prow[st * 16 + quad * 4 + r] = f2bf_bits(pp);
                    }
            }
            psum += __shfl_xor(psum, 16, 64);
            psum += __shfl_xor(psum, 32, 64);
            lqt[qt] += psum;
        }

        // PV: A = P (wave-private LDS), B = V^T frag
        bf16x8 pf0 = *(const bf16x8*)(&Ps[wid][(0  + m16) * 40 + quad * 8]);
        bf16x8 pf1 = *(const bf16x8*)(&Ps[wid][(16 + m16) * 40 + quad * 8]);
        #pragma unroll
        for (int dt = 0; dt < 8; ++dt) {
            int row = dt * 16 + m16;
            bf16x8 vf = *(const bf16x8*)(&Vt[row * 72 + quad * 8 + ((row >> 3) & 1) * 32]);
            accO[0][dt] = __builtin_amdgcn_mfma_f32_16x16x32_bf16(pf0, vf, accO[0][dt], 0, 0, 0);
            accO[1][dt] = __builtin_amdgcn_mfma_f32_16x16x32_bf16(pf1, vf, accO[1][dt], 0, 0, 0);
        }
    }

    // epilogue: O /= l
    #pragma unroll
    for (int qt = 0; qt < 2; ++qt) {
        float li[4];
        #pragma unroll
        for (int r = 0; r < 4; ++r)
            li[r] = 1.0f / __shfl(lqt[qt], quad * 4 + r, 64);
        #pragma unroll
        for (int r = 0; r < 4; ++r) {
            int t = qb_global + wid * 32 + qt * 16 + quad * 4 + r;
            __hip_bfloat16* op = out + (size_t)t * 3072 + h * 128 + m16;
            #pragma unroll
            for (int dt = 0; dt < 8; ++dt)
                op[dt * 16] = __float2bfloat16(accO[qt][dt][r] * li[r]);
        }
    }
}

// ---------------------------------------------------------------------------
extern "C" void kernel_launch(void* const* d_in, const int* in_sizes, int n_in,
                              void* d_out, int out_size, void* d_ws, size_t ws_size,
                              hipStream_t stream) {
    const float* hidden = (const float*)d_in[0];
    const float* w_qkv  = (const float*)d_in[1];
    const float* b_qkv  = (const float*)d_in[2];
    const float* w_o    = (const float*)d_in[3];
    const float* b_o    = (const float*)d_in[4];
    const float* cosb   = (const float*)d_in[5];
    const float* sinb   = (const float*)d_in[6];
    const int* seq_len_p = (const int*)d_in[7];
    const int* window_p  = (const int*)d_in[8];

    const int HID  = in_sizes[4];            // 3072
    const int NQKV = in_sizes[2];            // 3584
    const int T    = in_sizes[0] / HID;      // 4096

    size_t off = 0;
    auto alloc = [&](size_t bytes) {
        char* p = (char*)d_ws + off;
        off = (off + bytes + 255) & ~(size_t)255;
        return p;
    };
    __hip_bfloat16* qkv      = (__hip_bfloat16*)alloc((size_t)T * NQKV * 2);
    __hip_bfloat16* attn_out = (__hip_bfloat16*)alloc((size_t)T * HID * 2);
    __hip_bfloat16* hid_bf = (__hip_bfloat16*)alloc((size_t)T * HID * 2);
    __hip_bfloat16* wq_bf  = (__hip_bfloat16*)alloc((size_t)NQKV * HID * 2);
    __hip_bfloat16* wo_bf  = (__hip_bfloat16*)alloc((size_t)HID * HID * 2);
    const bool pre = (ws_size >= off);

    dim3 blk(256);

    if (pre) {
        int n8h = T * HID / 8, n8q = NQKV * HID / 8, n8o = HID * HID / 8;
        int n8 = n8h + n8q + n8o;
        cvt3_f32_bf16<<<dim3((n8 + 255) / 256), blk, 0, stream>>>(
            hidden, (short*)hid_bf, n8h, w_qkv, (short*)wq_bf, n8q,
            w_o, (short*)wo_bf, n8o);
        gemm_bt_lds<__hip_bfloat16><<<dim3(NQKV / 128, T / 128), blk, 0, stream>>>(
            hid_bf, wq_bf, b_qkv, qkv, T, NQKV, HID);
    } else {
        gemm_bt_bias<float, float, __hip_bfloat16>
            <<<dim3(NQKV / 128, T / 128), blk, 0, stream>>>(
            hidden, w_qkv, b_qkv, qkv, T, NQKV, HID);
    }

    int total = T * 26 * 8;
    rope_kernel<<<dim3((total + 255) / 256), blk, 0, stream>>>(qkv, cosb, sinb, T);

    attn_kernel<<<dim3(T / 128, 24), blk, 0, stream>>>(qkv, attn_out, seq_len_p, window_p);

    if (pre) {
        gemm_bt_lds<float><<<dim3(HID / 128, T / 128), blk, 0, stream>>>(
            attn_out, wo_bf, b_o, (float*)d_out, T, HID, HID);
    } else {
        gemm_bt_bias<__hip_bfloat16, float, float>
            <<<dim3(HID / 128, T / 128), blk, 0, stream>>>(
            attn_out, w_o, b_o, (float*)d_out, T, HID, HID);
    }
}